// Round 8
// baseline (343.812 us; speedup 1.0000x reference)
//
#include <hip/hip_runtime.h>

typedef unsigned short u16;
typedef __attribute__((ext_vector_type(8))) short short8;
typedef __attribute__((ext_vector_type(8))) unsigned short ushort8;
typedef __attribute__((ext_vector_type(4))) float f32x4;
typedef __attribute__((ext_vector_type(4))) unsigned short u16x4;

#define DEV static __device__ __forceinline__

DEV u16 f2bf(float f){
    unsigned u = __float_as_uint(f);
    u += 0x7fffu + ((u >> 16) & 1u);   // round-to-nearest-even
    return (u16)(u >> 16);
}
DEV float bf2f(u16 h){ return __uint_as_float(((unsigned)h) << 16); }
DEV float sigm(float v){ return 1.f / (1.f + __expf(-v)); }

DEV f32x4 MF(short8 a, short8 b, f32x4 c){
    return __builtin_amdgcn_mfma_f32_16x16x32_bf16(a, b, c, 0, 0, 0);
}
DEV void gload16(const void* g, u16* l){
    __builtin_amdgcn_global_load_lds(
        (const __attribute__((address_space(1))) void*)g,
        (__attribute__((address_space(3))) void*)l, 16, 0, 0);
}

#define SBAR()   asm volatile("s_barrier" ::: "memory")
#define WVM(n)   asm volatile("s_waitcnt vmcnt(" #n ")" ::: "memory")
#define WLG(n)   asm volatile("s_waitcnt lgkmcnt(" #n ")" ::: "memory")
#define SCB()    __builtin_amdgcn_sched_barrier(0)

constexpr int Bn = 8, Sn = 2048, Dn = 1024;
constexpr int CH = 128, NC = Sn / CH;          // 16 chunks along S
constexpr size_t NTOK = (size_t)Bn * Sn;       // 16384 rows

// ---------------- weight convert + transpose: w[K,N] f32 -> wt[N,K] bf16 ----
__global__ __launch_bounds__(256) void k_wcvt(const float* __restrict__ w,
                                              u16* __restrict__ wt,
                                              int Kd, int Nd)
{
    __shared__ float tile[32][33];
    int nbn = Nd / 32;
    int bk = blockIdx.x / nbn, bn = blockIdx.x % nbn;
    int lx = threadIdx.x & 31, ly = threadIdx.x >> 5;   // 32 x 8
    #pragma unroll
    for (int i = 0; i < 32; i += 8)
        tile[ly + i][lx] = w[(size_t)(bk * 32 + ly + i) * Nd + bn * 32 + lx];
    __syncthreads();
    #pragma unroll
    for (int i = 0; i < 32; i += 8)
        wt[(size_t)(bn * 32 + ly + i) * Kd + bk * 32 + lx] = f2bf(tile[lx][ly + i]);
}

// ---------------- cumulative average (3-phase chunked scan) -----------------
__global__ __launch_bounds__(256) void k_psum(const float* __restrict__ x,
                                              float* __restrict__ part)
{
    int bx = blockIdx.x;
    int dblk = bx & 3; bx >>= 2;
    int c = bx & (NC - 1), b = bx >> 4;
    int d = dblk * 256 + threadIdx.x;
    const float* px = x + ((size_t)b * Sn + (size_t)c * CH) * Dn + d;
    float s = 0.f;
    #pragma unroll 4
    for (int i = 0; i < CH; i++) s += px[(size_t)i * Dn];
    part[((size_t)b * NC + c) * Dn + d] = s;
}

__global__ __launch_bounds__(256) void k_pscan(float* part)
{
    int g = blockIdx.x * 256 + threadIdx.x;   // 8192 columns
    int b = g >> 10, d = g & 1023;
    float run = 0.f;
    #pragma unroll
    for (int c = 0; c < NC; c++){
        size_t idx = ((size_t)b * NC + c) * Dn + d;
        float v = part[idx]; part[idx] = run; run += v;
    }
}

// avg (bf16) + fused x->cat[:,0:1024] bf16 write
__global__ __launch_bounds__(256) void k_avg(const float* __restrict__ x,
                                             const float* __restrict__ part,
                                             u16* __restrict__ avg,
                                             u16* __restrict__ cat)
{
    int bx = blockIdx.x;
    int dblk = bx & 3; bx >>= 2;
    int c = bx & (NC - 1), b = bx >> 4;
    int d = dblk * 256 + threadIdx.x;
    const float* px = x   + ((size_t)b * Sn + (size_t)c * CH) * Dn + d;
    u16*         pa = avg + ((size_t)b * Sn + (size_t)c * CH) * Dn + d;
    u16*         pc = cat + ((size_t)b * Sn + (size_t)c * CH) * 2048 + d;
    float run = part[((size_t)b * NC + c) * Dn + d];
    for (int i = 0; i < CH; i++){
        float v = px[(size_t)i * Dn];
        run += v;
        int s = c * CH + i;
        pa[(size_t)i * Dn] = f2bf(run / (float)(s + 1));
        pc[(size_t)i * 2048] = f2bf(v);
    }
}

// ---------------- layernorm: avg bf16 -> ln bf16 ----------------------------
__global__ __launch_bounds__(256) void k_ln(const u16* __restrict__ avg,
                                            const float* __restrict__ g,
                                            const float* __restrict__ bta,
                                            u16* __restrict__ out)
{
    size_t row = blockIdx.x;
    int t = threadIdx.x;
    u16x4 hv = ((const u16x4*)(avg + row * Dn))[t];
    float4 v = { bf2f(hv[0]), bf2f(hv[1]), bf2f(hv[2]), bf2f(hv[3]) };
    float s = v.x + v.y + v.z + v.w;
    float q = v.x * v.x + v.y * v.y + v.z * v.z + v.w * v.w;
    #pragma unroll
    for (int o = 32; o > 0; o >>= 1){
        s += __shfl_down(s, o, 64);
        q += __shfl_down(q, o, 64);
    }
    __shared__ float rs[4], rq[4];
    __shared__ float smu, srstd;
    int wid = t >> 6, lane = t & 63;
    if (lane == 0){ rs[wid] = s; rq[wid] = q; }
    __syncthreads();
    if (t == 0){
        float S = rs[0] + rs[1] + rs[2] + rs[3];
        float Q = rq[0] + rq[1] + rq[2] + rq[3];
        float mu = S * (1.f / Dn);
        float var = Q * (1.f / Dn) - mu * mu;
        smu = mu; srstd = rsqrtf(var + 1e-6f);
    }
    __syncthreads();
    float mu = smu, rstd = srstd;
    int d0 = t * 4;
    float4 gg = ((const float4*)g)[t];
    float4 bb = ((const float4*)bta)[t];
    u16x4 o;
    o[0] = f2bf((v.x - mu) * rstd * gg.x + bb.x);
    o[1] = f2bf((v.y - mu) * rstd * gg.y + bb.y);
    o[2] = f2bf((v.z - mu) * rstd * gg.z + bb.z);
    o[3] = f2bf((v.w - mu) * rstd * gg.w + bb.w);
    *(u16x4*)(out + row * Dn + d0) = o;
}

// ---------------- BMx256xK=32-step GEMM, 2-blocks/CU occupancy design -------
// C = A[M,K] x Bt[N,K]^T + bias. 512 thr = 8 waves (2M x 4N),
// wave tile (BM/2)x64, acc[MFR][4], MFR = BM/32. One vmcnt(0)+barrier per
// 32-K tile (loads are a full tile old; co-resident block hides the rest).
// LDS: 2 x (BM+256)x32x2B = 64 KB (BM=256) / 48 KB (BM=128) -> 2 blocks/CU.
// Linear LDS layout (row stride 64B alternates bank halves -> <=2-way, free).
// EPI 1: ob = bf16(relu(v))                                  (inter)
// EPI 2: v += bf2f(resid); of = v; ob[2N,+N] = bf16(v)       (avg_out + cat)
// EPI 3: paired-panel gating, two-pass all-wave bf16 LDS exchange
template<int EPI, int BM>
__global__ __launch_bounds__(512, 2)
void k_gemm(const u16* __restrict__ A, const u16* __restrict__ Bt,
            const float* __restrict__ bias,
            float* __restrict__ of, u16* __restrict__ ob,
            const u16* __restrict__ resid,
            int M, int N, int K)
{
    constexpr int MFR  = BM / 32;          // a-frags per wave (8 | 4)
    constexpr int AL   = BM / 128;         // A gload16 per thread (2 | 1)
    constexpr int HALF = (BM + 256) * 32;  // elems per LDS buffer
    __shared__ u16 smem[2 * HALF];

    int nbn = (EPI == 3) ? 8 : (N >> 8);
    int nwg = (M / BM) * nbn;
    int bid = blockIdx.x;
    int swz = (bid & 7) * (nwg >> 3) + (bid >> 3);
    int bm = swz / nbn, bn = swz - bm * nbn;
    int m0 = bm * BM;
    int n0 = (EPI == 3) ? (bn << 7) : (bn << 8);

    int tid  = threadIdx.x;
    int wid  = tid >> 6, lane = tid & 63;
    int wm   = wid >> 2, wn = wid & 3;
    int fr   = lane & 15, q = lane >> 4;

    // staging (linear LDS; wave-uniform dst base + lane*16)
    int l4 = (lane & 3) << 4;              // byte col within 64B row
    int lr = lane >> 2;                    // row within 16-row chunk
    size_t K2 = (size_t)K * 2;
    const char* gA = (const char*)A + (size_t)(m0 + wid * (BM / 8) + lr) * K2 + l4;
    int brow = n0 + wid * 32 + lr;
    if (EPI == 3 && wid >= 4) brow += 896; // fg panel rows: 1024+n0+(wid-4)*32
    const char* gB = (const char*)Bt + (size_t)brow * K2 + l4;
    int aDst = (wid * (BM / 8)) * 32;      // elems
    int bDst = BM * 32 + (wid * 32) * 32;

    // fragment read offsets (elems)
    int aOff = (wm * (BM / 2) + fr) * 32 + (q << 3);
    int bOff = BM * 32 + (wn * 64 + fr) * 32 + (q << 3);

    f32x4 acc[MFR][4] = {};
    short8 af[MFR], bf[4];
    int NT = K >> 5;

#define STAGE(t) {                                                          \
    u16* _bp = smem + (((t) & 1) ? HALF : 0);                               \
    _Pragma("unroll")                                                       \
    for (int j = 0; j < AL; j++)                                            \
        gload16(gA + (size_t)(t) * 64 + (size_t)j * 16 * K2,                \
                _bp + aDst + j * 512);                                      \
    _Pragma("unroll")                                                       \
    for (int j = 0; j < 2; j++)                                             \
        gload16(gB + (size_t)(t) * 64 + (size_t)j * 16 * K2,                \
                _bp + bDst + j * 512);                                      \
}

    STAGE(0);
    for (int t = 0; t < NT; ++t){
        WVM(0); SBAR();                    // tile t staged everywhere
        if (t + 1 < NT) STAGE(t + 1);      // into the other buffer
        const u16* cp = smem + ((t & 1) ? HALF : 0);
        #pragma unroll
        for (int ni = 0; ni < 4; ni++)
            bf[ni] = *(const short8*)&cp[bOff + ni * 512];
        #pragma unroll
        for (int mi = 0; mi < 4; mi++)
            af[mi] = *(const short8*)&cp[aOff + mi * 512];
        WLG(0); SCB();
        __builtin_amdgcn_s_setprio(1);
        #pragma unroll
        for (int mi = 0; mi < 4; mi++)
            #pragma unroll
            for (int ni = 0; ni < 4; ni++)
                acc[mi][ni] = MF(af[mi], bf[ni], acc[mi][ni]);
        __builtin_amdgcn_s_setprio(0);
        if constexpr (MFR == 8){
            #pragma unroll
            for (int mi = 0; mi < 4; mi++)
                af[mi + 4] = *(const short8*)&cp[aOff + (mi + 4) * 512];
            WLG(0); SCB();
            __builtin_amdgcn_s_setprio(1);
            #pragma unroll
            for (int mi = 0; mi < 4; mi++)
                #pragma unroll
                for (int ni = 0; ni < 4; ni++)
                    acc[mi + 4][ni] = MF(af[mi + 4], bf[ni], acc[mi + 4][ni]);
            __builtin_amdgcn_s_setprio(0);
        }
    }

    int col = lane & 15, rb = q * 4;

    if constexpr (EPI == 3){
        // two-pass exchange: pass p handles rows [p*128,(p+1)*128)
        u16* s_in = smem;                  // [128][128] bf16, 32 KB
        u16* s_fg = smem + 16384;          // 32 KB
        float bv[4];
        #pragma unroll
        for (int ni = 0; ni < 4; ni++){
            int c = (wn & 1) * 64 + ni * 16 + col;
            bv[ni] = bias[((wn < 2) ? n0 : 1024 + n0) + c];
        }
        #pragma unroll
        for (int p = 0; p < 2; p++){
            SBAR();                        // prior reads of smem complete
            if (wm == p){
                #pragma unroll
                for (int mi = 0; mi < 8; mi++){
                    #pragma unroll
                    for (int ni = 0; ni < 4; ni++){
                        int c  = (wn & 1) * 64 + ni * 16 + col;
                        u16* dst = (wn < 2) ? s_in : s_fg;
                        #pragma unroll
                        for (int r = 0; r < 4; r++){
                            int row = mi * 16 + rb + r;          // 0..127
                            int cpx = c ^ (((row >> 2) & 3) << 4);
                            dst[row * 128 + cpx] =
                                f2bf(sigm(acc[mi][ni][r] + bv[ni]));
                        }
                    }
                }
            }
            WLG(0); SBAR();
            // combine: 8 waves x 16 rows each, vectorized
            #pragma unroll
            for (int rg = 0; rg < 4; rg++){
                int row_l = wid * 16 + rg * 4 + q;               // 0..127
                int grow  = m0 + p * 128 + row_l;
                int c0 = fr * 8;
                int cpx = c0 ^ (((row_l >> 2) & 3) << 4);
                ushort8 iv = *(const ushort8*)&s_in[row_l * 128 + cpx];
                ushort8 fv = *(const ushort8*)&s_fg[row_l * 128 + cpx];
                size_t ga = (size_t)grow * 2048 + n0 + c0;       // cat row
                ushort8 xv = *(const ushort8*)&A[ga];
                ushort8 av = *(const ushort8*)&A[ga + 1024];
                size_t gb = (size_t)grow * Dn + n0 + c0;
                float4 o0, o1;
                o0.x = bf2f(iv[0]) * bf2f(xv[0]) + bf2f(fv[0]) * bf2f(av[0]);
                o0.y = bf2f(iv[1]) * bf2f(xv[1]) + bf2f(fv[1]) * bf2f(av[1]);
                o0.z = bf2f(iv[2]) * bf2f(xv[2]) + bf2f(fv[2]) * bf2f(av[2]);
                o0.w = bf2f(iv[3]) * bf2f(xv[3]) + bf2f(fv[3]) * bf2f(av[3]);
                o1.x = bf2f(iv[4]) * bf2f(xv[4]) + bf2f(fv[4]) * bf2f(av[4]);
                o1.y = bf2f(iv[5]) * bf2f(xv[5]) + bf2f(fv[5]) * bf2f(av[5]);
                o1.z = bf2f(iv[6]) * bf2f(xv[6]) + bf2f(fv[6]) * bf2f(av[6]);
                o1.w = bf2f(iv[7]) * bf2f(xv[7]) + bf2f(fv[7]) * bf2f(av[7]);
                *(float4*)&of[gb] = o0;
                *(float4*)&of[gb + 4] = o1;
            }
        }
        return;
    }

    #pragma unroll
    for (int mi = 0; mi < MFR; mi++){
        #pragma unroll
        for (int ni = 0; ni < 4; ni++){
            int gn = n0 + wn * 64 + ni * 16 + col;
            float bvv = bias[gn];
            #pragma unroll
            for (int r = 0; r < 4; r++){
                int gm = m0 + wm * (BM / 2) + mi * 16 + rb + r;
                float v = acc[mi][ni][r] + bvv;
                if constexpr (EPI == 1){
                    ob[(size_t)gm * N + gn] = f2bf(fmaxf(v, 0.f));
                } else {
                    v += bf2f(resid[(size_t)gm * N + gn]);
                    of[(size_t)gm * N + gn] = v;
                    ob[(size_t)gm * 2 * N + N + gn] = f2bf(v);
                }
            }
        }
    }
}

// ---------------- launch -----------------------------------------------------
extern "C" void kernel_launch(void* const* d_in, const int* in_sizes, int n_in,
                              void* d_out, int out_size, void* d_ws, size_t ws_size,
                              hipStream_t stream)
{
    const float* x   = (const float*)d_in[0];
    const float* w1  = (const float*)d_in[1];
    const float* b1  = (const float*)d_in[2];
    const float* w2  = (const float*)d_in[3];
    const float* b2  = (const float*)d_in[4];
    const float* lng = (const float*)d_in[5];
    const float* lnb = (const float*)d_in[6];
    const float* wg  = (const float*)d_in[7];
    const float* bg  = (const float*)d_in[8];

    float* gated   = (float*)d_out;                    // [16384,1024]
    float* avg_out = (float*)d_out + NTOK * Dn;        // [16384,1024]

    char* ws = (char*)d_ws;
    u16*   w1t   = (u16*)  (ws + (0ull   << 20));      // 2 MB
    u16*   w2t   = (u16*)  (ws + (2ull   << 20));      // 2 MB
    u16*   wgt   = (u16*)  (ws + (4ull   << 20));      // 8 MB
    float* part  = (float*)(ws + (12ull  << 20));      // 0.5 MB
    u16*   avg   = (u16*)  (ws + (16ull  << 20));      // 32 MB (bf16)
    u16*   ln    = (u16*)  (ws + (80ull  << 20));      // 32 MB
    u16*   inter = (u16*)  (ws + (112ull << 20));      // 32 MB
    u16*   cat   = (u16*)  (ws + (144ull << 20));      // 64 MB  -> total 208 MB

    // weights -> bf16 transposed [N,K]
    k_wcvt<<<dim3(32 * 32), 256, 0, stream>>>(w1, w1t, Dn, Dn);
    k_wcvt<<<dim3(32 * 32), 256, 0, stream>>>(w2, w2t, Dn, Dn);
    k_wcvt<<<dim3(64 * 64), 256, 0, stream>>>(wg, wgt, 2 * Dn, 2 * Dn);

    // cumulative average (+ fused x->cat bf16)
    k_psum <<<dim3(Bn * NC * 4), 256, 0, stream>>>(x, part);
    k_pscan<<<dim3(Bn * Dn / 256), 256, 0, stream>>>(part);
    k_avg  <<<dim3(Bn * NC * 4), 256, 0, stream>>>(x, part, avg, cat);

    // LN
    k_ln<<<dim3((int)NTOK), 256, 0, stream>>>(avg, lng, lnb, ln);

    // FFN GEMMs: BM=128, BN=256 -> grid 512 (2 blocks/CU resident)
    k_gemm<1, 128><<<dim3((int)(NTOK / 128) * (Dn / 256)), 512, 0, stream>>>(
        ln, w1t, b1, nullptr, inter, nullptr, (int)NTOK, Dn, Dn);
    k_gemm<2, 128><<<dim3((int)(NTOK / 128) * (Dn / 256)), 512, 0, stream>>>(
        inter, w2t, b2, avg_out, cat, avg, (int)NTOK, Dn, Dn);

    // gating GEMM: BM=256, 8 paired n-panels -> grid 512 (2 blocks/CU)
    k_gemm<3, 256><<<dim3((int)(NTOK / 256) * 8), 512, 0, stream>>>(
        cat, wgt, bg, gated, nullptr, nullptr, (int)NTOK, 2 * Dn, 2 * Dn);
}

// Round 10
// 311.219 us; speedup vs baseline: 1.1047x; 1.1047x over previous
//
#include <hip/hip_runtime.h>

typedef unsigned short u16;
typedef __attribute__((ext_vector_type(8))) short short8;
typedef __attribute__((ext_vector_type(8))) unsigned short ushort8;
typedef __attribute__((ext_vector_type(4))) float f32x4;
typedef __attribute__((ext_vector_type(4))) unsigned short u16x4;

#define DEV static __device__ __forceinline__

DEV u16 f2bf(float f){
    unsigned u = __float_as_uint(f);
    u += 0x7fffu + ((u >> 16) & 1u);   // round-to-nearest-even
    return (u16)(u >> 16);
}
DEV float bf2f(u16 h){ return __uint_as_float(((unsigned)h) << 16); }
DEV float sigm(float v){ return 1.f / (1.f + __expf(-v)); }

DEV f32x4 MF(short8 a, short8 b, f32x4 c){
    return __builtin_amdgcn_mfma_f32_16x16x32_bf16(a, b, c, 0, 0, 0);
}
DEV void gload16(const void* g, u16* l){
    __builtin_amdgcn_global_load_lds(
        (const __attribute__((address_space(1))) void*)g,
        (__attribute__((address_space(3))) void*)l, 16, 0, 0);
}
DEV void stage_half(const char* gp, size_t K2, u16* dst){
    gload16(gp, dst);
    gload16(gp + (K2 << 3), dst + 512);
}

#define SBAR()   asm volatile("s_barrier" ::: "memory")
#define WVM(n)   asm volatile("s_waitcnt vmcnt(" #n ")" ::: "memory")
#define WLG(n)   asm volatile("s_waitcnt lgkmcnt(" #n ")" ::: "memory")
#define SCB()    __builtin_amdgcn_sched_barrier(0)

constexpr int Bn = 8, Sn = 2048, Dn = 1024;
constexpr int CH = 64, NC = Sn / CH;           // 32 chunks along S
constexpr size_t NTOK = (size_t)Bn * Sn;       // 16384 rows

// ---------------- weight convert + transpose: w[K,N] f32 -> wt[N,K] bf16 ----
__global__ __launch_bounds__(256) void k_wcvt(const float* __restrict__ w,
                                              u16* __restrict__ wt,
                                              int Kd, int Nd)
{
    __shared__ float tile[32][33];
    int nbn = Nd / 32;
    int bk = blockIdx.x / nbn, bn = blockIdx.x % nbn;
    int lx = threadIdx.x & 31, ly = threadIdx.x >> 5;   // 32 x 8
    #pragma unroll
    for (int i = 0; i < 32; i += 8)
        tile[ly + i][lx] = w[(size_t)(bk * 32 + ly + i) * Nd + bn * 32 + lx];
    __syncthreads();
    #pragma unroll
    for (int i = 0; i < 32; i += 8)
        wt[(size_t)(bn * 32 + ly + i) * Kd + bk * 32 + lx] = f2bf(tile[lx][ly + i]);
}

// ---------------- cumulative average phase 1/2: chunk sums + exclusive scan -
__global__ __launch_bounds__(256) void k_psum(const float* __restrict__ x,
                                              float* __restrict__ part)
{
    int bx = blockIdx.x;
    int dblk = bx & 3; bx >>= 2;
    int c = bx & (NC - 1), b = bx >> 5;
    int d = dblk * 256 + threadIdx.x;
    const float* px = x + ((size_t)b * Sn + (size_t)c * CH) * Dn + d;
    float s = 0.f;
    #pragma unroll 4
    for (int i = 0; i < CH; i++) s += px[(size_t)i * Dn];
    part[((size_t)b * NC + c) * Dn + d] = s;
}

__global__ __launch_bounds__(256) void k_pscan(float* part)
{
    int g = blockIdx.x * 256 + threadIdx.x;   // 8192 columns
    int b = g >> 10, d = g & 1023;
    float run = 0.f;
    #pragma unroll
    for (int c = 0; c < NC; c++){
        size_t idx = ((size_t)b * NC + c) * Dn + d;
        float v = part[idx]; part[idx] = run; run += v;
    }
}

// ---------------- fused avg + LN + x->cat: one block per (b,chunk) ----------
// 256 threads, thread t owns cols [4t,4t+4). Per row: cumavg in f32 regs,
// row-wide mean/var via shfl + LDS (parity double-buffer, 1 barrier/row),
// writes: avg bf16 (gemm2 residual), cat[:,0:1024] = bf16(x), ln bf16.
__global__ __launch_bounds__(256) void k_avgln(const float* __restrict__ x,
                                               const float* __restrict__ part,
                                               const float* __restrict__ g,
                                               const float* __restrict__ bta,
                                               u16* __restrict__ avg,
                                               u16* __restrict__ cat,
                                               u16* __restrict__ ln)
{
    int blk = blockIdx.x;
    int c = blk & (NC - 1), b = blk >> 5;
    int t = threadIdx.x;
    int wid = t >> 6, lane = t & 63;
    int d0 = t * 4;
    size_t rowbase = (size_t)b * Sn + (size_t)c * CH;

    const float4* px = (const float4*)(x + rowbase * Dn + d0);
    u16* pa = avg + rowbase * Dn + d0;
    u16* pc = cat + rowbase * 2048 + d0;
    u16* pl = ln  + rowbase * Dn + d0;

    float4 run = ((const float4*)(part + ((size_t)b * NC + c) * Dn + d0))[0];
    float4 gg = ((const float4*)g)[t];
    float4 bb = ((const float4*)bta)[t];

    __shared__ float rs[2][4], rq[2][4];

    for (int i = 0; i < CH; i++){
        float4 v = px[(size_t)i * (Dn / 4)];
        run.x += v.x; run.y += v.y; run.z += v.z; run.w += v.w;
        int s = c * CH + i;
        float inv = 1.f / (float)(s + 1);
        float4 a = { run.x * inv, run.y * inv, run.z * inv, run.w * inv };

        float s4 = a.x + a.y + a.z + a.w;
        float q4 = a.x * a.x + a.y * a.y + a.z * a.z + a.w * a.w;
        #pragma unroll
        for (int o = 32; o > 0; o >>= 1){
            s4 += __shfl_down(s4, o, 64);
            q4 += __shfl_down(q4, o, 64);
        }
        int par = i & 1;
        if (lane == 0){ rs[par][wid] = s4; rq[par][wid] = q4; }
        __syncthreads();
        float mu = (rs[par][0] + rs[par][1] + rs[par][2] + rs[par][3]) * (1.f / Dn);
        float Q  = (rq[par][0] + rq[par][1] + rq[par][2] + rq[par][3]) * (1.f / Dn);
        float rstd = rsqrtf(Q - mu * mu + 1e-6f);

        u16x4 oa = { f2bf(a.x), f2bf(a.y), f2bf(a.z), f2bf(a.w) };
        u16x4 ox = { f2bf(v.x), f2bf(v.y), f2bf(v.z), f2bf(v.w) };
        u16x4 ol;
        ol[0] = f2bf((a.x - mu) * rstd * gg.x + bb.x);
        ol[1] = f2bf((a.y - mu) * rstd * gg.y + bb.y);
        ol[2] = f2bf((a.z - mu) * rstd * gg.z + bb.z);
        ol[3] = f2bf((a.w - mu) * rstd * gg.w + bb.w);
        *(u16x4*)(pa + (size_t)i * Dn)   = oa;
        *(u16x4*)(pc + (size_t)i * 2048) = ox;
        *(u16x4*)(pl + (size_t)i * Dn)   = ol;
    }
}

// ---------------- 256x256x64 MFMA GEMM, JIT-read 4-phase pipeline -----------
// (verified round-6 structure: stages t+1 into the OPPOSITE buffer, per-phase
//  counted WVM(4) -> race-free by construction)
//   P0: WVM(4);bar; stage A0(t+1); read a0,b0; MFMA a0xb0
//   P1: WVM(4);bar; stage B0(t+1); read a1;    MFMA a1xb0
//   P2: WVM(4);bar; stage A1(t+1); read b1;    MFMA a1xb1
//   P3:              stage B1(t+1);            MFMA a0xb1   (no wait/barrier)
// EPI 1: ob = bf16(relu(v))                                  (inter)
// EPI 2: v += bf2f(resid); of = v; ob[2N,+N] = bf16(v)       (avg_out + cat)
// EPI 3: paired-panel gating, all-wave bf16 LDS exchange; x/avg_out from cat
template<int EPI>
__global__ __launch_bounds__(512, 2)
void k_gemm(const u16* __restrict__ A, const u16* __restrict__ Bt,
            const float* __restrict__ bias,
            float* __restrict__ of, u16* __restrict__ ob,
            const u16* __restrict__ resid,
            int M, int N, int K)
{
    __shared__ u16 smem[2][2][2][8192];   // [buf][A|B][half][128r x 64c] 128 KB

    int nbn = (EPI == 3) ? 8 : (N >> 8);
    int nwg = (M >> 8) * nbn;
    int bid = blockIdx.x;
    int swz = (bid & 7) * (nwg >> 3) + (bid >> 3);
    int bm = swz / nbn, bn = swz - bm * nbn;
    int m0 = bm << 8;
    int n0 = (EPI == 3) ? (bn << 7) : (bn << 8);

    int tid  = threadIdx.x;
    int wid  = tid >> 6, lane = tid & 63;
    int wm   = wid >> 2, wn = wid & 3;
    int fr   = lane & 15, q = lane >> 4;

    // staging addresses (source pre-swizzled per rule #21; LDS linear)
    int srow = (wid << 4) + (lane >> 3);
    int cb   = ((lane & 7) << 4) ^ (((lane >> 3) & 7) << 4);
    size_t K2 = (size_t)K * 2;
    int b1base = (EPI == 3) ? (1024 + n0) : (n0 + 128);
    const char* gA0 = (const char*)A  + (size_t)(m0 + srow) * K2 + cb;
    const char* gA1 = (const char*)A  + (size_t)(m0 + 128 + srow) * K2 + cb;
    const char* gB0 = (const char*)Bt + (size_t)(n0 + srow) * K2 + cb;
    const char* gB1 = (const char*)Bt + (size_t)(b1base + srow) * K2 + cb;
    int w16 = wid << 10;

    // fragment reads: phys elem = logical ^ ((row&7)<<3); row&7 == lane&7
    int xorE = (lane & 7) << 3;
    int cbE0 = ((q << 3) ^ xorE);
    int cbE1 = cbE0 ^ 32;
    int aOff = (wm * 64 + fr) * 64;
    int bOff = (wn * 32 + fr) * 64;

    f32x4 acc[8][4] = {};
    short8 a0f[4][2], a1f[4][2], b0f[2][2], b1f[2][2];
    int NT = K >> 6;

#define ST_A0(t) stage_half(gA0 + (size_t)(t) * 128, K2, &smem[(t)&1][0][0][w16])
#define ST_A1(t) stage_half(gA1 + (size_t)(t) * 128, K2, &smem[(t)&1][0][1][w16])
#define ST_B0(t) stage_half(gB0 + (size_t)(t) * 128, K2, &smem[(t)&1][1][0][w16])
#define ST_B1(t) stage_half(gB1 + (size_t)(t) * 128, K2, &smem[(t)&1][1][1][w16])
#define RD_A(Fr, t, half) { const u16* _p = &smem[(t)&1][0][half][0];           \
    _Pragma("unroll") for (int i = 0; i < 4; i++){                              \
        Fr[i][0] = *(const short8*)&_p[aOff + i * 1024 + cbE0];                 \
        Fr[i][1] = *(const short8*)&_p[aOff + i * 1024 + cbE1]; } }
#define RD_B(Fr, t, half) { const u16* _p = &smem[(t)&1][1][half][0];           \
    _Pragma("unroll") for (int i = 0; i < 2; i++){                              \
        Fr[i][0] = *(const short8*)&_p[bOff + i * 1024 + cbE0];                 \
        Fr[i][1] = *(const short8*)&_p[bOff + i * 1024 + cbE1]; } }
#define MMQ(Af, Bf, mo, no)                                                     \
    __builtin_amdgcn_s_setprio(1);                                              \
    _Pragma("unroll") for (int k = 0; k < 2; k++)                               \
        _Pragma("unroll") for (int mi = 0; mi < 4; mi++)                        \
            _Pragma("unroll") for (int ni = 0; ni < 2; ni++)                    \
                acc[mi+(mo)][ni+(no)] = MF(Af[mi][k], Bf[ni][k],                \
                                           acc[mi+(mo)][ni+(no)]);              \
    __builtin_amdgcn_s_setprio(0);

    // prologue: tile 0's four halves, in read order (ledger anchor)
    ST_A0(0); ST_B0(0); ST_A1(0); ST_B1(0);

    for (int t = 0; t + 1 < NT; ++t){
        // P0: Q00
        WVM(4); SBAR();
        ST_A0(t + 1);
        RD_A(a0f, t, 0);
        RD_B(b0f, t, 0);
        WLG(0); SCB();
        MMQ(a0f, b0f, 0, 0);
        // P1: Q10
        WVM(4); SBAR();
        ST_B0(t + 1);
        RD_A(a1f, t, 1);
        WLG(0); SCB();
        MMQ(a1f, b0f, 4, 0);
        // P2: Q11
        WVM(4); SBAR();
        ST_A1(t + 1);
        RD_B(b1f, t, 1);
        WLG(0); SCB();
        MMQ(a1f, b1f, 4, 2);
        // P3: Q01 (pure MFMA)
        ST_B1(t + 1);
        MMQ(a0f, b1f, 0, 2);
    }
    {   // last tile: no stages, exact tail waits
        int t = NT - 1;
        WVM(4); SBAR();
        RD_A(a0f, t, 0);
        RD_B(b0f, t, 0);
        WLG(0); SCB();
        MMQ(a0f, b0f, 0, 0);
        WVM(2); SBAR();
        RD_A(a1f, t, 1);
        WLG(0); SCB();
        MMQ(a1f, b0f, 4, 0);
        WVM(0); SBAR();
        RD_B(b1f, t, 1);
        WLG(0); SCB();
        MMQ(a1f, b1f, 4, 2);
        MMQ(a0f, b1f, 0, 2);
    }

    int col = lane & 15, rb = q * 4;

    if constexpr (EPI == 3){
        u16* s_in = &smem[0][0][0][0];        // [256][128] bf16, 64 KB
        u16* s_fg = s_in + 32768;             // 64 KB
        float bi[2], bf_[2];
        #pragma unroll
        for (int ni = 0; ni < 2; ni++){
            bi[ni]  = bias[n0 + wn * 32 + ni * 16 + col];
            bf_[ni] = bias[1024 + n0 + wn * 32 + ni * 16 + col];
        }
        SBAR();   // all waves done reading K-tile LDS
        #pragma unroll
        for (int mi = 0; mi < 8; mi++){
            int lrow = ((mi & 4) << 5) + wm * 64 + ((mi & 3) << 4) + rb;
            #pragma unroll
            for (int ni = 0; ni < 2; ni++){
                int c  = wn * 32 + ni * 16 + col;
                int cp = c ^ (q << 4);
                #pragma unroll
                for (int r = 0; r < 4; r++){
                    int row = lrow + r;
                    s_in[row * 128 + cp] = f2bf(sigm(acc[mi][ni][r] + bi[ni]));
                    s_fg[row * 128 + cp] = f2bf(sigm(acc[mi][ni + 2][r] + bf_[ni]));
                }
            }
        }
        WLG(0); SBAR();
        int rbase = wid * 32;
        #pragma unroll
        for (int rg = 0; rg < 8; rg++){
            int b4  = rbase + rg * 4;
            int row = b4 + (lane >> 4);
            int sw  = ((b4 >> 2) & 3) << 4;
            int c0  = (lane & 15) * 8;
            int cp  = c0 ^ sw;
            ushort8 iv = *(const ushort8*)&s_in[row * 128 + cp];
            ushort8 fv = *(const ushort8*)&s_fg[row * 128 + cp];
            size_t ga = (size_t)(m0 + row) * 2048 + n0 + c0;   // cat row base
            ushort8 xv = *(const ushort8*)&A[ga];
            ushort8 av = *(const ushort8*)&A[ga + 1024];
            size_t gb = (size_t)(m0 + row) * Dn + n0 + c0;
            float4 o0, o1;
            o0.x = bf2f(iv[0]) * bf2f(xv[0]) + bf2f(fv[0]) * bf2f(av[0]);
            o0.y = bf2f(iv[1]) * bf2f(xv[1]) + bf2f(fv[1]) * bf2f(av[1]);
            o0.z = bf2f(iv[2]) * bf2f(xv[2]) + bf2f(fv[2]) * bf2f(av[2]);
            o0.w = bf2f(iv[3]) * bf2f(xv[3]) + bf2f(fv[3]) * bf2f(av[3]);
            o1.x = bf2f(iv[4]) * bf2f(xv[4]) + bf2f(fv[4]) * bf2f(av[4]);
            o1.y = bf2f(iv[5]) * bf2f(xv[5]) + bf2f(fv[5]) * bf2f(av[5]);
            o1.z = bf2f(iv[6]) * bf2f(xv[6]) + bf2f(fv[6]) * bf2f(av[6]);
            o1.w = bf2f(iv[7]) * bf2f(xv[7]) + bf2f(fv[7]) * bf2f(av[7]);
            *(float4*)&of[gb] = o0;
            *(float4*)&of[gb + 4] = o1;
        }
        return;
    }

    #pragma unroll
    for (int mi = 0; mi < 8; mi++){
        int lrow = m0 + ((mi & 4) << 5) + wm * 64 + ((mi & 3) << 4) + rb;
        #pragma unroll
        for (int ni = 0; ni < 4; ni++){
            int gn = n0 + ((ni & 2) << 6) + wn * 32 + ((ni & 1) << 4) + col;
            float bv = bias[gn];
            #pragma unroll
            for (int r = 0; r < 4; r++){
                int gm = lrow + r;
                float v = acc[mi][ni][r] + bv;
                if constexpr (EPI == 1){
                    ob[(size_t)gm * N + gn] = f2bf(fmaxf(v, 0.f));
                } else {
                    v += bf2f(resid[(size_t)gm * N + gn]);
                    of[(size_t)gm * N + gn] = v;
                    ob[(size_t)gm * 2 * N + N + gn] = f2bf(v);
                }
            }
        }
    }
}

// ---------------- launch -----------------------------------------------------
extern "C" void kernel_launch(void* const* d_in, const int* in_sizes, int n_in,
                              void* d_out, int out_size, void* d_ws, size_t ws_size,
                              hipStream_t stream)
{
    const float* x   = (const float*)d_in[0];
    const float* w1  = (const float*)d_in[1];
    const float* b1  = (const float*)d_in[2];
    const float* w2  = (const float*)d_in[3];
    const float* b2  = (const float*)d_in[4];
    const float* lng = (const float*)d_in[5];
    const float* lnb = (const float*)d_in[6];
    const float* wg  = (const float*)d_in[7];
    const float* bg  = (const float*)d_in[8];

    float* gated   = (float*)d_out;                    // [16384,1024]
    float* avg_out = (float*)d_out + NTOK * Dn;        // [16384,1024]

    char* ws = (char*)d_ws;
    u16*   w1t   = (u16*)  (ws + (0ull   << 20));      // 2 MB
    u16*   w2t   = (u16*)  (ws + (2ull   << 20));      // 2 MB
    u16*   wgt   = (u16*)  (ws + (4ull   << 20));      // 8 MB
    float* part  = (float*)(ws + (12ull  << 20));      // 1 MB
    u16*   avg   = (u16*)  (ws + (16ull  << 20));      // 32 MB (bf16)
    u16*   ln    = (u16*)  (ws + (80ull  << 20));      // 32 MB
    u16*   inter = (u16*)  (ws + (112ull << 20));      // 32 MB
    u16*   cat   = (u16*)  (ws + (144ull << 20));      // 64 MB  -> total 208 MB

    // weights -> bf16 transposed [N,K]
    k_wcvt<<<dim3(32 * 32), 256, 0, stream>>>(w1, w1t, Dn, Dn);
    k_wcvt<<<dim3(32 * 32), 256, 0, stream>>>(w2, w2t, Dn, Dn);
    k_wcvt<<<dim3(64 * 64), 256, 0, stream>>>(wg, wgt, 2 * Dn, 2 * Dn);

    // cumulative average + fused LN + x->cat
    k_psum <<<dim3(Bn * NC * 4), 256, 0, stream>>>(x, part);
    k_pscan<<<dim3(Bn * Dn / 256), 256, 0, stream>>>(part);
    k_avgln<<<dim3(Bn * NC), 256, 0, stream>>>(x, part, lng, lnb, avg, cat, ln);

    // FFN GEMMs (256x256 tiles, 512 threads)
    k_gemm<1><<<dim3((int)(NTOK / 256) * (Dn / 256)), 512, 0, stream>>>(
        ln, w1t, b1, nullptr, inter, nullptr, (int)NTOK, Dn, Dn);
    k_gemm<2><<<dim3((int)(NTOK / 256) * (Dn / 256)), 512, 0, stream>>>(
        inter, w2t, b2, avg_out, cat, avg, (int)NTOK, Dn, Dn);

    // gating GEMM, fused sigmoid-combine epilogue (writes gated directly)
    k_gemm<3><<<dim3((int)(NTOK / 256) * 8), 512, 0, stream>>>(
        cat, wgt, bg, gated, nullptr, nullptr, (int)NTOK, 2 * Dn, 2 * Dn);
}

// Round 11
// 297.790 us; speedup vs baseline: 1.1545x; 1.0451x over previous
//
#include <hip/hip_runtime.h>

typedef unsigned short u16;
typedef __attribute__((ext_vector_type(8))) short short8;
typedef __attribute__((ext_vector_type(8))) unsigned short ushort8;
typedef __attribute__((ext_vector_type(4))) float f32x4;
typedef __attribute__((ext_vector_type(4))) unsigned short u16x4;

#define DEV static __device__ __forceinline__

DEV u16 f2bf(float f){
    unsigned u = __float_as_uint(f);
    u += 0x7fffu + ((u >> 16) & 1u);   // round-to-nearest-even
    return (u16)(u >> 16);
}
DEV float bf2f(u16 h){ return __uint_as_float(((unsigned)h) << 16); }
DEV float sigm(float v){ return 1.f / (1.f + __expf(-v)); }

DEV f32x4 MF(short8 a, short8 b, f32x4 c){
    return __builtin_amdgcn_mfma_f32_16x16x32_bf16(a, b, c, 0, 0, 0);
}
DEV void gload16(const void* g, u16* l){
    __builtin_amdgcn_global_load_lds(
        (const __attribute__((address_space(1))) void*)g,
        (__attribute__((address_space(3))) void*)l, 16, 0, 0);
}
DEV void stage_half(const char* gp, size_t K2, u16* dst){
    gload16(gp, dst);
    gload16(gp + (K2 << 3), dst + 512);
}

#define SBAR()   asm volatile("s_barrier" ::: "memory")
#define WVM(n)   asm volatile("s_waitcnt vmcnt(" #n ")" ::: "memory")
#define WLG(n)   asm volatile("s_waitcnt lgkmcnt(" #n ")" ::: "memory")
#define SCB()    __builtin_amdgcn_sched_barrier(0)

constexpr int Bn = 8, Sn = 2048, Dn = 1024;
constexpr int CH = 128, NC = Sn / CH;          // 16 chunks along S
constexpr size_t NTOK = (size_t)Bn * Sn;       // 16384 rows

// ---------------- merged weight convert+transpose: 3 weights, 1 launch ------
// blocks [0,1024): w1 (1024x1024); [1024,2048): w2; [2048,6144): wg (2048^2)
__global__ __launch_bounds__(256) void k_wcvt3(const float* __restrict__ w1,
                                               const float* __restrict__ w2,
                                               const float* __restrict__ wg,
                                               u16* __restrict__ w1t,
                                               u16* __restrict__ w2t,
                                               u16* __restrict__ wgt)
{
    __shared__ float tile[32][33];
    int bid = blockIdx.x;
    const float* w; u16* wt; int Nd;
    if (bid < 1024){ w = w1; wt = w1t; Nd = 1024; }
    else if (bid < 2048){ w = w2; wt = w2t; Nd = 1024; bid -= 1024; }
    else { w = wg; wt = wgt; Nd = 2048; bid -= 2048; }
    int nbn = Nd / 32;
    int bk = bid / nbn, bn = bid % nbn;
    int lx = threadIdx.x & 31, ly = threadIdx.x >> 5;   // 32 x 8
    #pragma unroll
    for (int i = 0; i < 32; i += 8)
        tile[ly + i][lx] = w[(size_t)(bk * 32 + ly + i) * Nd + bn * 32 + lx];
    __syncthreads();
    #pragma unroll
    for (int i = 0; i < 32; i += 8)
        wt[(size_t)(bn * 32 + ly + i) * Nd + bk * 32 + lx] = f2bf(tile[lx][ly + i]);
}

// ---------------- cumulative average (3-phase chunked scan) -----------------
__global__ __launch_bounds__(256) void k_psum(const float* __restrict__ x,
                                              float* __restrict__ part)
{
    int bx = blockIdx.x;
    int dblk = bx & 3; bx >>= 2;
    int c = bx & (NC - 1), b = bx >> 4;
    int d = dblk * 256 + threadIdx.x;
    const float* px = x + ((size_t)b * Sn + (size_t)c * CH) * Dn + d;
    float s = 0.f;
    #pragma unroll 4
    for (int i = 0; i < CH; i++) s += px[(size_t)i * Dn];
    part[((size_t)b * NC + c) * Dn + d] = s;
}

// batched scan: 16 independent loads -> register scan -> 16 stores
__global__ __launch_bounds__(256) void k_pscan(float* part)
{
    int g = blockIdx.x * 256 + threadIdx.x;   // 8192 columns
    int b = g >> 10, d = g & 1023;
    float v[NC];
    size_t base = (size_t)b * NC * Dn + d;
    #pragma unroll
    for (int c = 0; c < NC; c++) v[c] = part[base + (size_t)c * Dn];
    float run = 0.f;
    #pragma unroll
    for (int c = 0; c < NC; c++){ float t = v[c]; v[c] = run; run += t; }
    #pragma unroll
    for (int c = 0; c < NC; c++) part[base + (size_t)c * Dn] = v[c];
}

// avg (bf16) + fused x->cat[:,0:1024] bf16 write
__global__ __launch_bounds__(256) void k_avg(const float* __restrict__ x,
                                             const float* __restrict__ part,
                                             u16* __restrict__ avg,
                                             u16* __restrict__ cat)
{
    int bx = blockIdx.x;
    int dblk = bx & 3; bx >>= 2;
    int c = bx & (NC - 1), b = bx >> 4;
    int d = dblk * 256 + threadIdx.x;
    const float* px = x   + ((size_t)b * Sn + (size_t)c * CH) * Dn + d;
    u16*         pa = avg + ((size_t)b * Sn + (size_t)c * CH) * Dn + d;
    u16*         pc = cat + ((size_t)b * Sn + (size_t)c * CH) * 2048 + d;
    float run = part[((size_t)b * NC + c) * Dn + d];
    for (int i = 0; i < CH; i++){
        float v = px[(size_t)i * Dn];
        run += v;
        int s = c * CH + i;
        pa[(size_t)i * Dn] = f2bf(run / (float)(s + 1));
        pc[(size_t)i * 2048] = f2bf(v);
    }
}

// ---------------- layernorm: avg bf16 -> ln bf16 ----------------------------
__global__ __launch_bounds__(256) void k_ln(const u16* __restrict__ avg,
                                            const float* __restrict__ g,
                                            const float* __restrict__ bta,
                                            u16* __restrict__ out)
{
    size_t row = blockIdx.x;
    int t = threadIdx.x;
    u16x4 hv = ((const u16x4*)(avg + row * Dn))[t];
    float4 v = { bf2f(hv[0]), bf2f(hv[1]), bf2f(hv[2]), bf2f(hv[3]) };
    float s = v.x + v.y + v.z + v.w;
    float q = v.x * v.x + v.y * v.y + v.z * v.z + v.w * v.w;
    #pragma unroll
    for (int o = 32; o > 0; o >>= 1){
        s += __shfl_down(s, o, 64);
        q += __shfl_down(q, o, 64);
    }
    __shared__ float rs[4], rq[4];
    __shared__ float smu, srstd;
    int wid = t >> 6, lane = t & 63;
    if (lane == 0){ rs[wid] = s; rq[wid] = q; }
    __syncthreads();
    if (t == 0){
        float S = rs[0] + rs[1] + rs[2] + rs[3];
        float Q = rq[0] + rq[1] + rq[2] + rq[3];
        float mu = S * (1.f / Dn);
        float var = Q * (1.f / Dn) - mu * mu;
        smu = mu; srstd = rsqrtf(var + 1e-6f);
    }
    __syncthreads();
    float mu = smu, rstd = srstd;
    int d0 = t * 4;
    float4 gg = ((const float4*)g)[t];
    float4 bb = ((const float4*)bta)[t];
    u16x4 o;
    o[0] = f2bf((v.x - mu) * rstd * gg.x + bb.x);
    o[1] = f2bf((v.y - mu) * rstd * gg.y + bb.y);
    o[2] = f2bf((v.z - mu) * rstd * gg.z + bb.z);
    o[3] = f2bf((v.w - mu) * rstd * gg.w + bb.w);
    *(u16x4*)(out + row * Dn + d0) = o;
}

// ---------------- 256x256x64 MFMA GEMM, JIT-read 4-phase pipeline -----------
// (verified round-6 structure: stages t+1 into the OPPOSITE buffer, per-phase
//  counted WVM(4) -> race-free by construction)
//   P0: WVM(4);bar; stage A0(t+1); read a0,b0; MFMA a0xb0
//   P1: WVM(4);bar; stage B0(t+1); read a1;    MFMA a1xb0
//   P2: WVM(4);bar; stage A1(t+1); read b1;    MFMA a1xb1
//   P3:              stage B1(t+1);            MFMA a0xb1   (no wait/barrier)
// EPI 1: ob = bf16(relu(v))                                  (inter)
// EPI 2: v += bf2f(resid); of = v; ob[2N,+N] = bf16(v)       (avg_out + cat)
// EPI 3: paired-panel gating, all-wave bf16 LDS exchange; x/avg_out from cat
template<int EPI>
__global__ __launch_bounds__(512, 2)
void k_gemm(const u16* __restrict__ A, const u16* __restrict__ Bt,
            const float* __restrict__ bias,
            float* __restrict__ of, u16* __restrict__ ob,
            const u16* __restrict__ resid,
            int M, int N, int K)
{
    __shared__ u16 smem[2][2][2][8192];   // [buf][A|B][half][128r x 64c] 128 KB

    int nbn = (EPI == 3) ? 8 : (N >> 8);
    int nwg = (M >> 8) * nbn;
    int bid = blockIdx.x;
    int swz = (bid & 7) * (nwg >> 3) + (bid >> 3);
    int bm = swz / nbn, bn = swz - bm * nbn;
    int m0 = bm << 8;
    int n0 = (EPI == 3) ? (bn << 7) : (bn << 8);

    int tid  = threadIdx.x;
    int wid  = tid >> 6, lane = tid & 63;
    int wm   = wid >> 2, wn = wid & 3;
    int fr   = lane & 15, q = lane >> 4;

    // staging addresses (source pre-swizzled per rule #21; LDS linear)
    int srow = (wid << 4) + (lane >> 3);
    int cb   = ((lane & 7) << 4) ^ (((lane >> 3) & 7) << 4);
    size_t K2 = (size_t)K * 2;
    int b1base = (EPI == 3) ? (1024 + n0) : (n0 + 128);
    const char* gA0 = (const char*)A  + (size_t)(m0 + srow) * K2 + cb;
    const char* gA1 = (const char*)A  + (size_t)(m0 + 128 + srow) * K2 + cb;
    const char* gB0 = (const char*)Bt + (size_t)(n0 + srow) * K2 + cb;
    const char* gB1 = (const char*)Bt + (size_t)(b1base + srow) * K2 + cb;
    int w16 = wid << 10;

    // fragment reads: phys elem = logical ^ ((row&7)<<3); row&7 == lane&7
    int xorE = (lane & 7) << 3;
    int cbE0 = ((q << 3) ^ xorE);
    int cbE1 = cbE0 ^ 32;
    int aOff = (wm * 64 + fr) * 64;
    int bOff = (wn * 32 + fr) * 64;

    f32x4 acc[8][4] = {};
    short8 a0f[4][2], a1f[4][2], b0f[2][2], b1f[2][2];
    int NT = K >> 6;

#define ST_A0(t) stage_half(gA0 + (size_t)(t) * 128, K2, &smem[(t)&1][0][0][w16])
#define ST_A1(t) stage_half(gA1 + (size_t)(t) * 128, K2, &smem[(t)&1][0][1][w16])
#define ST_B0(t) stage_half(gB0 + (size_t)(t) * 128, K2, &smem[(t)&1][1][0][w16])
#define ST_B1(t) stage_half(gB1 + (size_t)(t) * 128, K2, &smem[(t)&1][1][1][w16])
#define RD_A(Fr, t, half) { const u16* _p = &smem[(t)&1][0][half][0];           \
    _Pragma("unroll") for (int i = 0; i < 4; i++){                              \
        Fr[i][0] = *(const short8*)&_p[aOff + i * 1024 + cbE0];                 \
        Fr[i][1] = *(const short8*)&_p[aOff + i * 1024 + cbE1]; } }
#define RD_B(Fr, t, half) { const u16* _p = &smem[(t)&1][1][half][0];           \
    _Pragma("unroll") for (int i = 0; i < 2; i++){                              \
        Fr[i][0] = *(const short8*)&_p[bOff + i * 1024 + cbE0];                 \
        Fr[i][1] = *(const short8*)&_p[bOff + i * 1024 + cbE1]; } }
#define MMQ(Af, Bf, mo, no)                                                     \
    __builtin_amdgcn_s_setprio(1);                                              \
    _Pragma("unroll") for (int k = 0; k < 2; k++)                               \
        _Pragma("unroll") for (int mi = 0; mi < 4; mi++)                        \
            _Pragma("unroll") for (int ni = 0; ni < 2; ni++)                    \
                acc[mi+(mo)][ni+(no)] = MF(Af[mi][k], Bf[ni][k],                \
                                           acc[mi+(mo)][ni+(no)]);              \
    __builtin_amdgcn_s_setprio(0);

    // prologue: tile 0's four halves, in read order (ledger anchor)
    ST_A0(0); ST_B0(0); ST_A1(0); ST_B1(0);

    for (int t = 0; t + 1 < NT; ++t){
        // P0: Q00
        WVM(4); SBAR();
        ST_A0(t + 1);
        RD_A(a0f, t, 0);
        RD_B(b0f, t, 0);
        WLG(0); SCB();
        MMQ(a0f, b0f, 0, 0);
        // P1: Q10
        WVM(4); SBAR();
        ST_B0(t + 1);
        RD_A(a1f, t, 1);
        WLG(0); SCB();
        MMQ(a1f, b0f, 4, 0);
        // P2: Q11
        WVM(4); SBAR();
        ST_A1(t + 1);
        RD_B(b1f, t, 1);
        WLG(0); SCB();
        MMQ(a1f, b1f, 4, 2);
        // P3: Q01 (pure MFMA)
        ST_B1(t + 1);
        MMQ(a0f, b1f, 0, 2);
    }
    {   // last tile: no stages, exact tail waits
        int t = NT - 1;
        WVM(4); SBAR();
        RD_A(a0f, t, 0);
        RD_B(b0f, t, 0);
        WLG(0); SCB();
        MMQ(a0f, b0f, 0, 0);
        WVM(2); SBAR();
        RD_A(a1f, t, 1);
        WLG(0); SCB();
        MMQ(a1f, b0f, 4, 0);
        WVM(0); SBAR();
        RD_B(b1f, t, 1);
        WLG(0); SCB();
        MMQ(a1f, b1f, 4, 2);
        MMQ(a0f, b1f, 0, 2);
    }

    int col = lane & 15, rb = q * 4;

    if constexpr (EPI == 3){
        u16* s_in = &smem[0][0][0][0];        // [256][128] bf16, 64 KB
        u16* s_fg = s_in + 32768;             // 64 KB
        float bi[2], bf_[2];
        #pragma unroll
        for (int ni = 0; ni < 2; ni++){
            bi[ni]  = bias[n0 + wn * 32 + ni * 16 + col];
            bf_[ni] = bias[1024 + n0 + wn * 32 + ni * 16 + col];
        }
        SBAR();   // all waves done reading K-tile LDS
        #pragma unroll
        for (int mi = 0; mi < 8; mi++){
            int lrow = ((mi & 4) << 5) + wm * 64 + ((mi & 3) << 4) + rb;
            #pragma unroll
            for (int ni = 0; ni < 2; ni++){
                int c  = wn * 32 + ni * 16 + col;
                int cp = c ^ (q << 4);
                #pragma unroll
                for (int r = 0; r < 4; r++){
                    int row = lrow + r;
                    s_in[row * 128 + cp] = f2bf(sigm(acc[mi][ni][r] + bi[ni]));
                    s_fg[row * 128 + cp] = f2bf(sigm(acc[mi][ni + 2][r] + bf_[ni]));
                }
            }
        }
        WLG(0); SBAR();
        int rbase = wid * 32;
        #pragma unroll
        for (int rg = 0; rg < 8; rg++){
            int b4  = rbase + rg * 4;
            int row = b4 + (lane >> 4);
            int sw  = ((b4 >> 2) & 3) << 4;
            int c0  = (lane & 15) * 8;
            int cp  = c0 ^ sw;
            ushort8 iv = *(const ushort8*)&s_in[row * 128 + cp];
            ushort8 fv = *(const ushort8*)&s_fg[row * 128 + cp];
            size_t ga = (size_t)(m0 + row) * 2048 + n0 + c0;   // cat row base
            ushort8 xv = *(const ushort8*)&A[ga];
            ushort8 av = *(const ushort8*)&A[ga + 1024];
            size_t gb = (size_t)(m0 + row) * Dn + n0 + c0;
            float4 o0, o1;
            o0.x = bf2f(iv[0]) * bf2f(xv[0]) + bf2f(fv[0]) * bf2f(av[0]);
            o0.y = bf2f(iv[1]) * bf2f(xv[1]) + bf2f(fv[1]) * bf2f(av[1]);
            o0.z = bf2f(iv[2]) * bf2f(xv[2]) + bf2f(fv[2]) * bf2f(av[2]);
            o0.w = bf2f(iv[3]) * bf2f(xv[3]) + bf2f(fv[3]) * bf2f(av[3]);
            o1.x = bf2f(iv[4]) * bf2f(xv[4]) + bf2f(fv[4]) * bf2f(av[4]);
            o1.y = bf2f(iv[5]) * bf2f(xv[5]) + bf2f(fv[5]) * bf2f(av[5]);
            o1.z = bf2f(iv[6]) * bf2f(xv[6]) + bf2f(fv[6]) * bf2f(av[6]);
            o1.w = bf2f(iv[7]) * bf2f(xv[7]) + bf2f(fv[7]) * bf2f(av[7]);
            *(float4*)&of[gb] = o0;
            *(float4*)&of[gb + 4] = o1;
        }
        return;
    }

    #pragma unroll
    for (int mi = 0; mi < 8; mi++){
        int lrow = m0 + ((mi & 4) << 5) + wm * 64 + ((mi & 3) << 4) + rb;
        #pragma unroll
        for (int ni = 0; ni < 4; ni++){
            int gn = n0 + ((ni & 2) << 6) + wn * 32 + ((ni & 1) << 4) + col;
            float bv = bias[gn];
            #pragma unroll
            for (int r = 0; r < 4; r++){
                int gm = lrow + r;
                float v = acc[mi][ni][r] + bv;
                if constexpr (EPI == 1){
                    ob[(size_t)gm * N + gn] = f2bf(fmaxf(v, 0.f));
                } else {
                    v += bf2f(resid[(size_t)gm * N + gn]);
                    of[(size_t)gm * N + gn] = v;
                    ob[(size_t)gm * 2 * N + N + gn] = f2bf(v);
                }
            }
        }
    }
}

// ---------------- launch -----------------------------------------------------
extern "C" void kernel_launch(void* const* d_in, const int* in_sizes, int n_in,
                              void* d_out, int out_size, void* d_ws, size_t ws_size,
                              hipStream_t stream)
{
    const float* x   = (const float*)d_in[0];
    const float* w1  = (const float*)d_in[1];
    const float* b1  = (const float*)d_in[2];
    const float* w2  = (const float*)d_in[3];
    const float* b2  = (const float*)d_in[4];
    const float* lng = (const float*)d_in[5];
    const float* lnb = (const float*)d_in[6];
    const float* wg  = (const float*)d_in[7];
    const float* bg  = (const float*)d_in[8];

    float* gated   = (float*)d_out;                    // [16384,1024]
    float* avg_out = (float*)d_out + NTOK * Dn;        // [16384,1024]

    char* ws = (char*)d_ws;
    u16*   w1t   = (u16*)  (ws + (0ull   << 20));      // 2 MB
    u16*   w2t   = (u16*)  (ws + (2ull   << 20));      // 2 MB
    u16*   wgt   = (u16*)  (ws + (4ull   << 20));      // 8 MB
    float* part  = (float*)(ws + (12ull  << 20));      // 0.5 MB
    u16*   avg   = (u16*)  (ws + (16ull  << 20));      // 32 MB (bf16)
    u16*   ln    = (u16*)  (ws + (80ull  << 20));      // 32 MB
    u16*   inter = (u16*)  (ws + (112ull << 20));      // 32 MB
    u16*   cat   = (u16*)  (ws + (144ull << 20));      // 64 MB  -> total 208 MB

    // weights -> bf16 transposed [N,K] (single merged launch)
    k_wcvt3<<<dim3(6144), 256, 0, stream>>>(w1, w2, wg, w1t, w2t, wgt);

    // cumulative average (+ fused x->cat bf16)
    k_psum <<<dim3(Bn * NC * 4), 256, 0, stream>>>(x, part);
    k_pscan<<<dim3(Bn * Dn / 256), 256, 0, stream>>>(part);
    k_avg  <<<dim3(Bn * NC * 4), 256, 0, stream>>>(x, part, avg, cat);

    // LN
    k_ln<<<dim3((int)NTOK), 256, 0, stream>>>(avg, lng, lnb, ln);

    // FFN GEMMs (256x256 tiles, 512 threads)
    k_gemm<1><<<dim3((int)(NTOK / 256) * (Dn / 256)), 512, 0, stream>>>(
        ln, w1t, b1, nullptr, inter, nullptr, (int)NTOK, Dn, Dn);
    k_gemm<2><<<dim3((int)(NTOK / 256) * (Dn / 256)), 512, 0, stream>>>(
        inter, w2t, b2, avg_out, cat, avg, (int)NTOK, Dn, Dn);

    // gating GEMM, fused sigmoid-combine epilogue (writes gated directly)
    k_gemm<3><<<dim3((int)(NTOK / 256) * 8), 512, 0, stream>>>(
        cat, wgt, bg, gated, nullptr, nullptr, (int)NTOK, 2 * Dn, 2 * Dn);
}